// Round 1
// baseline (632.207 us; speedup 1.0000x reference)
//
#include <hip/hip_runtime.h>
#include <hip/hip_bf16.h>
#include <hip/hip_cooperative_groups.h>

namespace cg = cooperative_groups;

// Problem constants (match reference)
constexpr int cB  = 8;
constexpr int cS  = 4096;
constexpr int cH  = 768;
constexpr int cNH = 12;
constexpr int cL  = 2;
constexpr int cNS = 64;
constexpr int cDH = 64;
constexpr int cM  = cB * cNS;  // 512 rows of activations

typedef __attribute__((ext_vector_type(8))) short bf16x8;
typedef __attribute__((ext_vector_type(4))) float f32x4;

// ---------------------------------------------------------------------------
// Shared phase bodies (identical math to the verified multi-kernel version).
// ---------------------------------------------------------------------------
struct AttnShared {
    float QP[cNS][cDH + 4];  // Q, later overlaid by P
    float Ks[cNS][cDH + 4];
    float Vt[cDH][cNS + 4];
};

// Fused qkv-GEMM + attention for one (batch, head). 256 threads.
// MFMA maps (m89/m91): a[j]=A[l15][q4*8+j], b[j]=Wt[l15][q4*8+j],
// D: col=l15, row=q4*4+r.
__device__ __forceinline__ void qkvattn_body(
    const __hip_bfloat16* __restrict__ x_bf,
    const __hip_bfloat16* __restrict__ wqkv,   // [3][H][H] bf16 (n-major)
    const float* __restrict__ bq, const float* __restrict__ bk,
    const float* __restrict__ bv,
    __hip_bfloat16* __restrict__ ctx_bf,
    int b, int hh, AttnShared& sh)
{
    int tid = threadIdx.x;
    int lane = tid & 63, wave = tid >> 6;
    int l15 = lane & 15, q4 = lane >> 4;

    const __hip_bfloat16* Arow[4];
    #pragma unroll
    for (int m = 0; m < 4; ++m)
        Arow[m] = x_bf + (size_t)(b * 64 + m * 16 + l15) * cH + q4 * 8;
    const __hip_bfloat16* Brow[3];
    int cmat[3], cnt_[3];
    #pragma unroll
    for (int j = 0; j < 3; ++j) {
        int c = wave * 3 + j;
        cmat[j] = c >> 2; cnt_[j] = c & 3;
        Brow[j] = wqkv + (size_t)cmat[j] * cH * cH
                       + (size_t)(hh * 64 + cnt_[j] * 16 + l15) * cH + q4 * 8;
    }

    f32x4 acc[3][4];
    #pragma unroll
    for (int j = 0; j < 3; ++j)
        #pragma unroll
        for (int m = 0; m < 4; ++m) acc[j][m] = (f32x4){0.f, 0.f, 0.f, 0.f};

    #pragma unroll 4
    for (int k0 = 0; k0 < cH; k0 += 32) {
        bf16x8 a[4], bb8[3];
        #pragma unroll
        for (int m = 0; m < 4; ++m) a[m] = *(const bf16x8*)(Arow[m] + k0);
        #pragma unroll
        for (int j = 0; j < 3; ++j) bb8[j] = *(const bf16x8*)(Brow[j] + k0);
        #pragma unroll
        for (int j = 0; j < 3; ++j)
            #pragma unroll
            for (int m = 0; m < 4; ++m)
                acc[j][m] = __builtin_amdgcn_mfma_f32_16x16x32_bf16(a[m], bb8[j], acc[j][m], 0, 0, 0);
    }

    const float scale = 0.125f;  // 1/sqrt(64)
    #pragma unroll
    for (int j = 0; j < 3; ++j) {
        int mat = cmat[j], nt = cnt_[j];
        int col_d = nt * 16 + l15;
        int col_g = hh * 64 + col_d;
        float bias = (mat == 0 ? bq : mat == 1 ? bk : bv)[col_g];
        #pragma unroll
        for (int m = 0; m < 4; ++m) {
            #pragma unroll
            for (int r = 0; r < 4; ++r) {
                int row_s = m * 16 + q4 * 4 + r;
                float v = acc[j][m][r] + bias;
                if (mat == 0)      sh.QP[row_s][col_d] = v * scale;
                else if (mat == 1) sh.Ks[row_s][col_d] = v;
                else               sh.Vt[col_d][row_s] = v;
            }
        }
    }
    __syncthreads();

    int tx = tid & 15, ty = tid >> 4;  // 16x16 threads, 4x4 microtiles
    float accs[4][4] = {};
    for (int d = 0; d < cDH; d += 4) {
        float4 qv[4], kv[4];
        #pragma unroll
        for (int i = 0; i < 4; ++i) qv[i] = *(const float4*)&sh.QP[ty * 4 + i][d];
        #pragma unroll
        for (int j = 0; j < 4; ++j) kv[j] = *(const float4*)&sh.Ks[tx + j * 16][d];
        #pragma unroll
        for (int i = 0; i < 4; ++i)
            #pragma unroll
            for (int j = 0; j < 4; ++j)
                accs[i][j] += qv[i].x * kv[j].x + qv[i].y * kv[j].y +
                              qv[i].z * kv[j].z + qv[i].w * kv[j].w;
    }
    __syncthreads();   // all QK^T reads done before P overlays Q
    #pragma unroll
    for (int i = 0; i < 4; ++i)
        #pragma unroll
        for (int j = 0; j < 4; ++j)
            sh.QP[ty * 4 + i][tx + j * 16] = accs[i][j];
    __syncthreads();

    {   // softmax: row = tid>>2, 16 cols/thread, quad shuffle
        int row = tid >> 2, jq = tid & 3;
        float e[16];
        float m = -1e30f;
        #pragma unroll
        for (int c = 0; c < 16; ++c) { e[c] = sh.QP[row][jq * 16 + c]; m = fmaxf(m, e[c]); }
        m = fmaxf(m, __shfl_xor(m, 1));
        m = fmaxf(m, __shfl_xor(m, 2));
        float s = 0.f;
        #pragma unroll
        for (int c = 0; c < 16; ++c) { e[c] = __expf(e[c] - m); s += e[c]; }
        s += __shfl_xor(s, 1);
        s += __shfl_xor(s, 2);
        float inv = 1.0f / s;
        #pragma unroll
        for (int c = 0; c < 16; ++c) sh.QP[row][jq * 16 + c] = e[c] * inv;
    }
    __syncthreads();

    float acco[4][4] = {};
    for (int c = 0; c < cNS; c += 4) {
        float4 p4[4], vt4[4];
        #pragma unroll
        for (int i = 0; i < 4; ++i) p4[i] = *(const float4*)&sh.QP[ty * 4 + i][c];
        #pragma unroll
        for (int j = 0; j < 4; ++j) vt4[j] = *(const float4*)&sh.Vt[tx + j * 16][c];
        #pragma unroll
        for (int i = 0; i < 4; ++i)
            #pragma unroll
            for (int j = 0; j < 4; ++j)
                acco[i][j] += p4[i].x * vt4[j].x + p4[i].y * vt4[j].y +
                              p4[i].z * vt4[j].z + p4[i].w * vt4[j].w;
    }
    size_t base = ((size_t)b * cNS) * cH + hh * cDH;
    #pragma unroll
    for (int i = 0; i < 4; ++i)
        #pragma unroll
        for (int j = 0; j < 4; ++j)
            ctx_bf[base + (size_t)(ty * 4 + i) * cH + tx + j * 16] =
                __float2bfloat16(acco[i][j]);
}

// O-GEMM + bias + GELU -> bf16 h. One (gx, gy) tile = 64 rows x 32 cols. 256 thr.
__device__ __forceinline__ void ogemm_body(
    const __hip_bfloat16* __restrict__ A,      // ctx_bf [M][H]
    const __hip_bfloat16* __restrict__ Wt,     // [H][H] n-major
    const float* __restrict__ bias,
    __hip_bfloat16* __restrict__ C,            // h bf16 [M][H]
    int gx, int gy)
{
    int lane = threadIdx.x & 63;
    int wave = threadIdx.x >> 6;
    int l15 = lane & 15, q4 = lane >> 4;
    int m0 = gy * 64 + wave * 16;
    int n0 = gx * 32;

    const __hip_bfloat16* Arow = A  + (size_t)(m0 + l15) * cH + q4 * 8;
    const __hip_bfloat16* Wr0  = Wt + (size_t)(n0 + l15) * cH + q4 * 8;
    const __hip_bfloat16* Wr1  = Wr0 + (size_t)16 * cH;

    f32x4 acc0 = {0.f, 0.f, 0.f, 0.f};
    f32x4 acc1 = {0.f, 0.f, 0.f, 0.f};
    #pragma unroll 8
    for (int k0 = 0; k0 < cH; k0 += 32) {
        bf16x8 a  = *(const bf16x8*)(Arow + k0);
        bf16x8 b0 = *(const bf16x8*)(Wr0 + k0);
        bf16x8 b1 = *(const bf16x8*)(Wr1 + k0);
        acc0 = __builtin_amdgcn_mfma_f32_16x16x32_bf16(a, b0, acc0, 0, 0, 0);
        acc1 = __builtin_amdgcn_mfma_f32_16x16x32_bf16(a, b1, acc1, 0, 0, 0);
    }
    #pragma unroll
    for (int nt = 0; nt < 2; ++nt) {
        const f32x4 acc = nt == 0 ? acc0 : acc1;
        int col = n0 + nt * 16 + l15;
        float bv = bias[col];
        #pragma unroll
        for (int r = 0; r < 4; ++r) {
            float v = acc[r] + bv;
            v = 0.5f * v * (1.0f + erff(v * 0.70710678118654752f));
            C[(size_t)(m0 + q4 * 4 + r) * cH + col] = __float2bfloat16(v);
        }
    }
}

// LayerNorm over H=768 (bf16 input) for one row. 256 threads.
__device__ __forceinline__ void ln_body(
    const __hip_bfloat16* __restrict__ h, const float* __restrict__ g,
    const float* __restrict__ bb, __hip_bfloat16* __restrict__ xb,
    float* __restrict__ outf, int row)
{
    const __hip_bfloat16* r = h + (size_t)row * cH;
    int tid = threadIdx.x;
    float v0 = __bfloat162float(r[tid]);
    float v1 = __bfloat162float(r[tid + 256]);
    float v2 = __bfloat162float(r[tid + 512]);
    float s = v0 + v1 + v2;
    __shared__ float red[4];
    #pragma unroll
    for (int o = 32; o; o >>= 1) s += __shfl_xor(s, o);
    if ((tid & 63) == 0) red[tid >> 6] = s;
    __syncthreads();
    float mu = (red[0] + red[1] + red[2] + red[3]) * (1.0f / 768.0f);
    float d0 = v0 - mu, d1 = v1 - mu, d2 = v2 - mu;
    float ss = d0 * d0 + d1 * d1 + d2 * d2;
    __syncthreads();
    #pragma unroll
    for (int o = 32; o; o >>= 1) ss += __shfl_xor(ss, o);
    if ((tid & 63) == 0) red[tid >> 6] = ss;
    __syncthreads();
    float var = (red[0] + red[1] + red[2] + red[3]) * (1.0f / 768.0f);
    float inv = rsqrtf(var + 1e-12f);
    float o0 = d0 * inv * g[tid]       + bb[tid];
    float o1 = d1 * inv * g[tid + 256] + bb[tid + 256];
    float o2 = d2 * inv * g[tid + 512] + bb[tid + 512];
    __hip_bfloat16* xr = xb + (size_t)row * cH;
    xr[tid]       = __float2bfloat16(o0);
    xr[tid + 256] = __float2bfloat16(o1);
    xr[tid + 512] = __float2bfloat16(o2);
    if (outf) {
        float* orow = outf + (size_t)row * cH;
        orow[tid] = o0; orow[tid + 256] = o1; orow[tid + 512] = o2;
    }
}

// ---------------------------------------------------------------------------
// MEGA: the whole pipeline in one cooperative kernel.
// 512 blocks x 256 threads = exactly 2 blocks/CU (LDS 52 KB/block, VGPR<=256
// via launch_bounds) -> co-residency guaranteed, hipLaunchCooperativeKernel
// validates. 6 grid.sync()s replace 6 inter-kernel boundaries.
// ---------------------------------------------------------------------------
union MegaShared {
    struct { int cnt; int list[cS]; } p;   // pooling: 16.4 KB
    float T[64][65];                       // wconv tile: 16.6 KB
    AttnShared a;                          // attention: 51.0 KB
};

__global__ __launch_bounds__(256, 2) void mega_kernel(
    const int* __restrict__ sent_ind, const float* __restrict__ sl,
    const float* __restrict__ Wq, const float* __restrict__ Wk,
    const float* __restrict__ Wv, const float* __restrict__ Wo,
    const float* __restrict__ bq, const float* __restrict__ bk,
    const float* __restrict__ bv, const float* __restrict__ bo,
    const float* __restrict__ ln_g, const float* __restrict__ ln_b,
    __hip_bfloat16* __restrict__ wt, __hip_bfloat16* __restrict__ x_bf,
    __hip_bfloat16* __restrict__ ctx_bf, __hip_bfloat16* __restrict__ hb,
    float* __restrict__ out)
{
    cg::grid_group grid = cg::this_grid();
    __shared__ MegaShared sh;
    const int tid = threadIdx.x;
    const int bid = blockIdx.x;

    // ---------------- Phase 0a: segment-mean pooling, one (b,n) per block ---
    {
        int b = bid >> 6, n = bid & (cNS - 1);
        if (tid == 0) sh.p.cnt = 0;
        __syncthreads();
        const int* si = sent_ind + (size_t)b * cS;
        for (int s = tid; s < cS; s += 256)
            if (s != 0 && si[s] == n) { int p = atomicAdd(&sh.p.cnt, 1); sh.p.list[p] = s; }
        __syncthreads();
        int c = sh.p.cnt;
        if (tid < 192) {
            const float* bbase = sl + (size_t)b * cS * cH;
            int col = tid * 4;
            float4 a0 = {0.f, 0.f, 0.f, 0.f};
            float4 a1 = {0.f, 0.f, 0.f, 0.f};
            float4 a2 = {0.f, 0.f, 0.f, 0.f};
            float4 a3 = {0.f, 0.f, 0.f, 0.f};
            int i = 0;
            for (; i + 4 <= c; i += 4) {
                float4 r0 = *(const float4*)(bbase + (size_t)sh.p.list[i + 0] * cH + col);
                float4 r1 = *(const float4*)(bbase + (size_t)sh.p.list[i + 1] * cH + col);
                float4 r2 = *(const float4*)(bbase + (size_t)sh.p.list[i + 2] * cH + col);
                float4 r3 = *(const float4*)(bbase + (size_t)sh.p.list[i + 3] * cH + col);
                a0.x += r0.x; a0.y += r0.y; a0.z += r0.z; a0.w += r0.w;
                a1.x += r1.x; a1.y += r1.y; a1.z += r1.z; a1.w += r1.w;
                a2.x += r2.x; a2.y += r2.y; a2.z += r2.z; a2.w += r2.w;
                a3.x += r3.x; a3.y += r3.y; a3.z += r3.z; a3.w += r3.w;
            }
            for (; i < c; ++i) {
                float4 r0 = *(const float4*)(bbase + (size_t)sh.p.list[i] * cH + col);
                a0.x += r0.x; a0.y += r0.y; a0.z += r0.z; a0.w += r0.w;
            }
            float inv = 1.0f / (float)c;
            __hip_bfloat16* xr = x_bf + (size_t)bid * cH + col;
            xr[0] = __float2bfloat16((a0.x + a1.x + a2.x + a3.x) * inv);
            xr[1] = __float2bfloat16((a0.y + a1.y + a2.y + a3.y) * inv);
            xr[2] = __float2bfloat16((a0.z + a1.z + a2.z + a3.z) * inv);
            xr[3] = __float2bfloat16((a0.w + a1.w + a2.w + a3.w) * inv);
        }
        __syncthreads();   // list dead before T overlays it
    }

    // ---------------- Phase 0b: weight transpose+convert, 1152 tiles --------
    for (int bi = bid; bi < 1152; bi += cM) {
        int bx = bi % 12, by = (bi / 12) % 12, mat = bi / 144;
        int layer = mat >> 2, which = mat & 3;
        const float* W = (which == 0 ? Wq : which == 1 ? Wk : which == 2 ? Wv : Wo)
                         + (size_t)layer * cH * cH;
        int k0 = by * 64, n0 = bx * 64;
        int r = tid >> 2, cb = (tid & 3) * 16;
        #pragma unroll
        for (int u = 0; u < 4; ++u) {
            float4 w4 = *(const float4*)(W + (size_t)(k0 + r) * cH + n0 + cb + u * 4);
            sh.T[r][cb + u * 4 + 0] = w4.x; sh.T[r][cb + u * 4 + 1] = w4.y;
            sh.T[r][cb + u * 4 + 2] = w4.z; sh.T[r][cb + u * 4 + 3] = w4.w;
        }
        __syncthreads();
        int nn = tid >> 2, kseg = (tid & 3) * 16;
        __hip_bfloat16 tmp[16] __attribute__((aligned(16)));
        #pragma unroll
        for (int j = 0; j < 16; ++j)
            tmp[j] = __float2bfloat16(sh.T[kseg + j][nn]);
        __hip_bfloat16* dst = wt + ((size_t)mat * cH + n0 + nn) * cH + k0 + kseg;
        *(bf16x8*)(dst)     = *(const bf16x8*)(tmp);
        *(bf16x8*)(dst + 8) = *(const bf16x8*)(tmp + 8);
        __syncthreads();   // before next tile overwrites T
    }
    grid.sync();           // x_bf + wt visible to everyone

    // ---------------- Layers ------------------------------------------------
    for (int layer = 0; layer < cL; ++layer) {
        const __hip_bfloat16* wqkv = wt + (size_t)(layer * 4) * cH * cH;
        const __hip_bfloat16* wto  = wt + (size_t)(layer * 4 + 3) * cH * cH;

        if (bid < cB * cNH)
            qkvattn_body(x_bf, wqkv,
                         bq + (size_t)layer * cH, bk + (size_t)layer * cH,
                         bv + (size_t)layer * cH, ctx_bf,
                         bid / cNH, bid % cNH, sh.a);
        grid.sync();       // ctx complete

        if (bid < 192)
            ogemm_body(ctx_bf, wto, bo + (size_t)layer * cH, hb,
                       bid % 24, bid / 24);
        grid.sync();       // h complete

        ln_body(hb, ln_g + (size_t)layer * cH, ln_b + (size_t)layer * cH,
                x_bf, (layer == cL - 1) ? out : nullptr, bid);
        if (layer != cL - 1) grid.sync();   // x ready for next layer's qkv
    }
}

// ---------------------------------------------------------------------------
// Fallback path: the proven 7-dispatch pipeline (unchanged), used only if the
// cooperative launch is rejected (e.g. capture doesn't support it).
// ---------------------------------------------------------------------------
union PrepShared {
    struct { int cnt; int list[cS]; float ps[192][4]; } p;   // 19.5 KB
    float T[2][64][65];                                      // 33.3 KB
};

__global__ __launch_bounds__(512) void prep_kernel(
    const int* __restrict__ sent_ind, const float* __restrict__ sl,
    __hip_bfloat16* __restrict__ xb,
    const float* __restrict__ Wq, const float* __restrict__ Wk,
    const float* __restrict__ Wv, const float* __restrict__ Wo,
    __hip_bfloat16* __restrict__ wt)
{
    __shared__ PrepShared sh;
    int tid = threadIdx.x;

    if (blockIdx.x < (unsigned)cM) {
        int bn = blockIdx.x;
        int b = bn >> 6, n = bn & (cNS - 1);
        if (tid == 0) sh.p.cnt = 0;
        __syncthreads();
        const int* si = sent_ind + (size_t)b * cS;
        for (int s = tid; s < cS; s += 512)
            if (s != 0 && si[s] == n) { int p = atomicAdd(&sh.p.cnt, 1); sh.p.list[p] = s; }
        __syncthreads();
        int c = sh.p.cnt;
        int grp = tid >> 8;
        int t   = tid & 255;
        int c0 = c >> 1;
        int lo = grp ? c0 : 0;
        int hi = grp ? c  : c0;
        float s0 = 0.f, s1 = 0.f, s2 = 0.f, s3 = 0.f;
        if (t < 192) {
            const float* bbase = sl + (size_t)b * cS * cH;
            int col = t * 4;
            float4 a0 = {0.f, 0.f, 0.f, 0.f};
            float4 a1 = {0.f, 0.f, 0.f, 0.f};
            float4 a2 = {0.f, 0.f, 0.f, 0.f};
            float4 a3 = {0.f, 0.f, 0.f, 0.f};
            int i = lo;
            for (; i + 4 <= hi; i += 4) {
                float4 r0 = *(const float4*)(bbase + (size_t)sh.p.list[i + 0] * cH + col);
                float4 r1 = *(const float4*)(bbase + (size_t)sh.p.list[i + 1] * cH + col);
                float4 r2 = *(const float4*)(bbase + (size_t)sh.p.list[i + 2] * cH + col);
                float4 r3 = *(const float4*)(bbase + (size_t)sh.p.list[i + 3] * cH + col);
                a0.x += r0.x; a0.y += r0.y; a0.z += r0.z; a0.w += r0.w;
                a1.x += r1.x; a1.y += r1.y; a1.z += r1.z; a1.w += r1.w;
                a2.x += r2.x; a2.y += r2.y; a2.z += r2.z; a2.w += r2.w;
                a3.x += r3.x; a3.y += r3.y; a3.z += r3.z; a3.w += r3.w;
            }
            for (; i < hi; ++i) {
                float4 r0 = *(const float4*)(bbase + (size_t)sh.p.list[i] * cH + col);
                a0.x += r0.x; a0.y += r0.y; a0.z += r0.z; a0.w += r0.w;
            }
            s0 = a0.x + a1.x + a2.x + a3.x;
            s1 = a0.y + a1.y + a2.y + a3.y;
            s2 = a0.z + a1.z + a2.z + a3.z;
            s3 = a0.w + a1.w + a2.w + a3.w;
        }
        if (grp == 1 && t < 192) {
            sh.p.ps[t][0] = s0; sh.p.ps[t][1] = s1;
            sh.p.ps[t][2] = s2; sh.p.ps[t][3] = s3;
        }
        __syncthreads();
        if (grp == 0 && t < 192) {
            float inv = 1.0f / (float)c;
            __hip_bfloat16* xr = xb + (size_t)bn * cH + t * 4;
            xr[0] = __float2bfloat16((s0 + sh.p.ps[t][0]) * inv);
            xr[1] = __float2bfloat16((s1 + sh.p.ps[t][1]) * inv);
            xr[2] = __float2bfloat16((s2 + sh.p.ps[t][2]) * inv);
            xr[3] = __float2bfloat16((s3 + sh.p.ps[t][3]) * inv);
        }
    } else {
        int sub = tid >> 8;
        int t   = tid & 255;
        int bi = (blockIdx.x - cM) * 2 + sub;
        int bx = bi % 12, by = (bi / 12) % 12, mat = bi / 144;
        int layer = mat >> 2, which = mat & 3;
        const float* W = (which == 0 ? Wq : which == 1 ? Wk : which == 2 ? Wv : Wo)
                         + (size_t)layer * cH * cH;
        int k0 = by * 64, n0 = bx * 64;
        int r = t >> 2, cb = (t & 3) * 16;
        #pragma unroll
        for (int u = 0; u < 4; ++u) {
            float4 w4 = *(const float4*)(W + (size_t)(k0 + r) * cH + n0 + cb + u * 4);
            sh.T[sub][r][cb + u * 4 + 0] = w4.x; sh.T[sub][r][cb + u * 4 + 1] = w4.y;
            sh.T[sub][r][cb + u * 4 + 2] = w4.z; sh.T[sub][r][cb + u * 4 + 3] = w4.w;
        }
        __syncthreads();
        int nn = t >> 2, kseg = (t & 3) * 16;
        __hip_bfloat16 tmp[16] __attribute__((aligned(16)));
        #pragma unroll
        for (int j = 0; j < 16; ++j)
            tmp[j] = __float2bfloat16(sh.T[sub][kseg + j][nn]);
        __hip_bfloat16* dst = wt + ((size_t)mat * cH + n0 + nn) * cH + k0 + kseg;
        *(bf16x8*)(dst)     = *(const bf16x8*)(tmp);
        *(bf16x8*)(dst + 8) = *(const bf16x8*)(tmp + 8);
    }
}

__global__ __launch_bounds__(256) void qkvattn_kernel(
    const __hip_bfloat16* __restrict__ x_bf,
    const __hip_bfloat16* __restrict__ wqkv,
    const float* __restrict__ bq, const float* __restrict__ bk,
    const float* __restrict__ bv,
    __hip_bfloat16* __restrict__ ctx_bf)
{
    __shared__ AttnShared sh;
    qkvattn_body(x_bf, wqkv, bq, bk, bv, ctx_bf,
                 blockIdx.x / cNH, blockIdx.x % cNH, sh);
}

__global__ __launch_bounds__(256) void ogemm_kernel(
    const __hip_bfloat16* __restrict__ A,
    const __hip_bfloat16* __restrict__ Wt,
    const float* __restrict__ bias,
    __hip_bfloat16* __restrict__ C)
{
    ogemm_body(A, Wt, bias, C, blockIdx.x, blockIdx.y);
}

__global__ __launch_bounds__(256) void ln_kernel(
    const __hip_bfloat16* __restrict__ h, const float* __restrict__ g,
    const float* __restrict__ bb, __hip_bfloat16* __restrict__ xb,
    float* __restrict__ outf)
{
    ln_body(h, g, bb, xb, outf, blockIdx.x);
}

// ---------------------------------------------------------------------------
extern "C" void kernel_launch(void* const* d_in, const int* in_sizes, int n_in,
                              void* d_out, int out_size, void* d_ws, size_t ws_size,
                              hipStream_t stream) {
    const int*   sent_ind = (const int*)d_in[0];
    const float* start    = (const float*)d_in[1];
    const float* Wq = (const float*)d_in[2];
    const float* bq = (const float*)d_in[3];
    const float* Wk = (const float*)d_in[4];
    const float* bk = (const float*)d_in[5];
    const float* Wv = (const float*)d_in[6];
    const float* bv = (const float*)d_in[7];
    const float* Wo = (const float*)d_in[8];
    const float* bo = (const float*)d_in[9];
    const float* ln_g = (const float*)d_in[10];
    const float* ln_b = (const float*)d_in[11];
    float* out = (float*)d_out;

    char* w = (char*)d_ws;
    __hip_bfloat16* wt     = (__hip_bfloat16*)w;                          // 8*H*H bf16
    __hip_bfloat16* x_bf   = (__hip_bfloat16*)(w + 9437184);              // M*H bf16
    __hip_bfloat16* ctx_bf = (__hip_bfloat16*)(w + 9437184 + 786432);     // M*H bf16
    __hip_bfloat16* hb     = (__hip_bfloat16*)(w + 9437184 + 2 * 786432); // M*H bf16

    void* kargs[] = {
        (void*)&sent_ind, (void*)&start,
        (void*)&Wq, (void*)&Wk, (void*)&Wv, (void*)&Wo,
        (void*)&bq, (void*)&bk, (void*)&bv, (void*)&bo,
        (void*)&ln_g, (void*)&ln_b,
        (void*)&wt, (void*)&x_bf, (void*)&ctx_bf, (void*)&hb, (void*)&out
    };
    hipError_t err = hipLaunchCooperativeKernel(
        (const void*)mega_kernel, dim3(cM), dim3(256), kargs, 0, stream);

    if (err != hipSuccess) {
        // Proven 7-dispatch fallback (== previous verified 284 us version).
        prep_kernel<<<cM + 576, 512, 0, stream>>>(sent_ind, start, x_bf,
                                                  Wq, Wk, Wv, Wo, wt);
        for (int i = 0; i < cL; ++i) {
            const __hip_bfloat16* wqkv = wt + (size_t)(i * 4) * cH * cH;
            const __hip_bfloat16* wto  = wt + (size_t)(i * 4 + 3) * cH * cH;
            qkvattn_kernel<<<cB * cNH, 256, 0, stream>>>(
                x_bf, wqkv, bq + (size_t)i * cH, bk + (size_t)i * cH,
                bv + (size_t)i * cH, ctx_bf);
            ogemm_kernel<<<dim3(24, 8), 256, 0, stream>>>(
                ctx_bf, wto, bo + (size_t)i * cH, hb);
            ln_kernel<<<cM, 256, 0, stream>>>(
                hb, ln_g + (size_t)i * cH, ln_b + (size_t)i * cH,
                x_bf, (i == cL - 1) ? out : nullptr);
        }
    }
}

// Round 3
// 324.547 us; speedup vs baseline: 1.9480x; 1.9480x over previous
//
#include <hip/hip_runtime.h>
#include <hip/hip_bf16.h>

// Problem constants (match reference)
constexpr int cB  = 8;
constexpr int cS  = 4096;
constexpr int cH  = 768;
constexpr int cNH = 12;
constexpr int cL  = 2;
constexpr int cNS = 64;
constexpr int cDH = 64;
constexpr int cM  = cB * cNS;  // 512 rows of activations

typedef __attribute__((ext_vector_type(8))) short bf16x8;
typedef __attribute__((ext_vector_type(4))) float f32x4;
typedef __attribute__((ext_vector_type(4))) unsigned short u16x4;

__device__ __forceinline__ float b2f(unsigned short u) {
    union { float f; unsigned int i; } x; x.i = (unsigned int)u << 16; return x.f;
}
__device__ __forceinline__ unsigned short f2b(float f) {
    __hip_bfloat16 h = __float2bfloat16(f);
    return *(unsigned short*)&h;
}

// ---------------------------------------------------------------------------
// 1) Fused prep (512 threads/block): blocks [0, 512) segment-mean pooling
//    (two 192-thread row-groups, 2x loads in flight, LDS combine);
//    blocks [512, 1088) weight transpose+convert, 2 tiles/block.
//    Block 0 additionally zeroes the 16 LN-drain counters (if provided).
// ---------------------------------------------------------------------------
union PrepShared {
    struct { int cnt; int list[cS]; float ps[192][4]; } p;   // 19.5 KB
    float T[2][64][65];                                      // 33.3 KB
};

__global__ __launch_bounds__(512) void prep_kernel(
    const int* __restrict__ sent_ind, const float* __restrict__ sl,
    __hip_bfloat16* __restrict__ xb,
    const float* __restrict__ Wq, const float* __restrict__ Wk,
    const float* __restrict__ Wv, const float* __restrict__ Wo,
    __hip_bfloat16* __restrict__ wt,
    int* __restrict__ lncnt)
{
    __shared__ PrepShared sh;
    int tid = threadIdx.x;

    if (lncnt && blockIdx.x == 0 && tid < 16) lncnt[tid] = 0;   // ws is poisoned

    if (blockIdx.x < (unsigned)cM) {
        // ---------------- pool ----------------
        int bn = blockIdx.x;
        int b = bn >> 6, n = bn & (cNS - 1);
        if (tid == 0) sh.p.cnt = 0;
        __syncthreads();
        const int* si = sent_ind + (size_t)b * cS;
        for (int s = tid; s < cS; s += 512)
            if (s != 0 && si[s] == n) { int p = atomicAdd(&sh.p.cnt, 1); sh.p.list[p] = s; }
        __syncthreads();
        int c = sh.p.cnt;
        int grp = tid >> 8;          // 0 or 1: row-group
        int t   = tid & 255;
        int c0 = c >> 1;
        int lo = grp ? c0 : 0;
        int hi = grp ? c  : c0;
        float s0 = 0.f, s1 = 0.f, s2 = 0.f, s3 = 0.f;
        if (t < 192) {
            const float* bbase = sl + (size_t)b * cS * cH;
            int col = t * 4;
            float4 a0 = {0.f, 0.f, 0.f, 0.f};
            float4 a1 = {0.f, 0.f, 0.f, 0.f};
            float4 a2 = {0.f, 0.f, 0.f, 0.f};
            float4 a3 = {0.f, 0.f, 0.f, 0.f};
            int i = lo;
            for (; i + 4 <= hi; i += 4) {
                float4 r0 = *(const float4*)(bbase + (size_t)sh.p.list[i + 0] * cH + col);
                float4 r1 = *(const float4*)(bbase + (size_t)sh.p.list[i + 1] * cH + col);
                float4 r2 = *(const float4*)(bbase + (size_t)sh.p.list[i + 2] * cH + col);
                float4 r3 = *(const float4*)(bbase + (size_t)sh.p.list[i + 3] * cH + col);
                a0.x += r0.x; a0.y += r0.y; a0.z += r0.z; a0.w += r0.w;
                a1.x += r1.x; a1.y += r1.y; a1.z += r1.z; a1.w += r1.w;
                a2.x += r2.x; a2.y += r2.y; a2.z += r2.z; a2.w += r2.w;
                a3.x += r3.x; a3.y += r3.y; a3.z += r3.z; a3.w += r3.w;
            }
            for (; i < hi; ++i) {
                float4 r0 = *(const float4*)(bbase + (size_t)sh.p.list[i] * cH + col);
                a0.x += r0.x; a0.y += r0.y; a0.z += r0.z; a0.w += r0.w;
            }
            s0 = a0.x + a1.x + a2.x + a3.x;
            s1 = a0.y + a1.y + a2.y + a3.y;
            s2 = a0.z + a1.z + a2.z + a3.z;
            s3 = a0.w + a1.w + a2.w + a3.w;
        }
        if (grp == 1 && t < 192) {
            sh.p.ps[t][0] = s0; sh.p.ps[t][1] = s1;
            sh.p.ps[t][2] = s2; sh.p.ps[t][3] = s3;
        }
        __syncthreads();
        if (grp == 0 && t < 192) {
            float inv = 1.0f / (float)c;
            __hip_bfloat16* xr = xb + (size_t)bn * cH + t * 4;
            xr[0] = __float2bfloat16((s0 + sh.p.ps[t][0]) * inv);
            xr[1] = __float2bfloat16((s1 + sh.p.ps[t][1]) * inv);
            xr[2] = __float2bfloat16((s2 + sh.p.ps[t][2]) * inv);
            xr[3] = __float2bfloat16((s3 + sh.p.ps[t][3]) * inv);
        }
    } else {
        // ---------------- wconv: 2 tiles per block ----------------
        int sub = tid >> 8;                         // which tile
        int t   = tid & 255;
        int bi = (blockIdx.x - cM) * 2 + sub;       // 0..1151 = (12 x 12 x 8)
        int bx = bi % 12, by = (bi / 12) % 12, mat = bi / 144;
        int layer = mat >> 2, which = mat & 3;
        const float* W = (which == 0 ? Wq : which == 1 ? Wk : which == 2 ? Wv : Wo)
                         + (size_t)layer * cH * cH;
        int k0 = by * 64, n0 = bx * 64;
        int r = t >> 2, cb = (t & 3) * 16;
        #pragma unroll
        for (int u = 0; u < 4; ++u) {
            float4 w4 = *(const float4*)(W + (size_t)(k0 + r) * cH + n0 + cb + u * 4);
            sh.T[sub][r][cb + u * 4 + 0] = w4.x; sh.T[sub][r][cb + u * 4 + 1] = w4.y;
            sh.T[sub][r][cb + u * 4 + 2] = w4.z; sh.T[sub][r][cb + u * 4 + 3] = w4.w;
        }
        __syncthreads();
        // lane writes 16 bf16 = 32 B contiguous (two 16-B stores)
        int nn = t >> 2, kseg = (t & 3) * 16;
        __hip_bfloat16 tmp[16] __attribute__((aligned(16)));
        #pragma unroll
        for (int j = 0; j < 16; ++j)
            tmp[j] = __float2bfloat16(sh.T[sub][kseg + j][nn]);
        __hip_bfloat16* dst = wt + ((size_t)mat * cH + n0 + nn) * cH + k0 + kseg;
        *(bf16x8*)(dst)     = *(const bf16x8*)(tmp);
        *(bf16x8*)(dst + 8) = *(const bf16x8*)(tmp + 8);
    }
}

// ---------------------------------------------------------------------------
// 2) Fused qkv-GEMM + attention.  One block per (batch, head) = 96 blocks.
//    (unchanged from the verified 285 us version)
// ---------------------------------------------------------------------------
struct AttnShared {
    float QP[cNS][cDH + 4];  // Q, later overlaid by P
    float Ks[cNS][cDH + 4];
    float Vt[cDH][cNS + 4];
};

__global__ __launch_bounds__(256) void qkvattn_kernel(
    const __hip_bfloat16* __restrict__ x_bf,
    const __hip_bfloat16* __restrict__ wqkv,   // [3][H][H] bf16 (n-major)
    const float* __restrict__ bq, const float* __restrict__ bk,
    const float* __restrict__ bv,
    __hip_bfloat16* __restrict__ ctx_bf)
{
    __shared__ AttnShared sh;
    int tid = threadIdx.x;
    int lane = tid & 63, wave = tid >> 6;
    int l15 = lane & 15, q4 = lane >> 4;
    int b = blockIdx.x / cNH, hh = blockIdx.x % cNH;

    const __hip_bfloat16* Arow[4];
    #pragma unroll
    for (int m = 0; m < 4; ++m)
        Arow[m] = x_bf + (size_t)(b * 64 + m * 16 + l15) * cH + q4 * 8;
    const __hip_bfloat16* Brow[3];
    int cmat[3], cnt_[3];
    #pragma unroll
    for (int j = 0; j < 3; ++j) {
        int c = wave * 3 + j;
        cmat[j] = c >> 2; cnt_[j] = c & 3;
        Brow[j] = wqkv + (size_t)cmat[j] * cH * cH
                       + (size_t)(hh * 64 + cnt_[j] * 16 + l15) * cH + q4 * 8;
    }

    f32x4 acc[3][4];
    #pragma unroll
    for (int j = 0; j < 3; ++j)
        #pragma unroll
        for (int m = 0; m < 4; ++m) acc[j][m] = (f32x4){0.f, 0.f, 0.f, 0.f};

    #pragma unroll 4
    for (int k0 = 0; k0 < cH; k0 += 32) {
        bf16x8 a[4], bb8[3];
        #pragma unroll
        for (int m = 0; m < 4; ++m) a[m] = *(const bf16x8*)(Arow[m] + k0);
        #pragma unroll
        for (int j = 0; j < 3; ++j) bb8[j] = *(const bf16x8*)(Brow[j] + k0);
        #pragma unroll
        for (int j = 0; j < 3; ++j)
            #pragma unroll
            for (int m = 0; m < 4; ++m)
                acc[j][m] = __builtin_amdgcn_mfma_f32_16x16x32_bf16(a[m], bb8[j], acc[j][m], 0, 0, 0);
    }

    const float scale = 0.125f;  // 1/sqrt(64)
    #pragma unroll
    for (int j = 0; j < 3; ++j) {
        int mat = cmat[j], nt = cnt_[j];
        int col_d = nt * 16 + l15;
        int col_g = hh * 64 + col_d;
        float bias = (mat == 0 ? bq : mat == 1 ? bk : bv)[col_g];
        #pragma unroll
        for (int m = 0; m < 4; ++m) {
            #pragma unroll
            for (int r = 0; r < 4; ++r) {
                int row_s = m * 16 + q4 * 4 + r;
                float v = acc[j][m][r] + bias;
                if (mat == 0)      sh.QP[row_s][col_d] = v * scale;
                else if (mat == 1) sh.Ks[row_s][col_d] = v;
                else               sh.Vt[col_d][row_s] = v;
            }
        }
    }
    __syncthreads();

    int tx = tid & 15, ty = tid >> 4;  // 16x16 threads, 4x4 microtiles
    float accs[4][4] = {};
    for (int d = 0; d < cDH; d += 4) {
        float4 qv[4], kv[4];
        #pragma unroll
        for (int i = 0; i < 4; ++i) qv[i] = *(const float4*)&sh.QP[ty * 4 + i][d];
        #pragma unroll
        for (int j = 0; j < 4; ++j) kv[j] = *(const float4*)&sh.Ks[tx + j * 16][d];
        #pragma unroll
        for (int i = 0; i < 4; ++i)
            #pragma unroll
            for (int j = 0; j < 4; ++j)
                accs[i][j] += qv[i].x * kv[j].x + qv[i].y * kv[j].y +
                              qv[i].z * kv[j].z + qv[i].w * kv[j].w;
    }
    __syncthreads();   // all QK^T reads done before P overlays Q
    #pragma unroll
    for (int i = 0; i < 4; ++i)
        #pragma unroll
        for (int j = 0; j < 4; ++j)
            sh.QP[ty * 4 + i][tx + j * 16] = accs[i][j];
    __syncthreads();

    {   // softmax: row = tid>>2, 16 cols/thread, quad shuffle
        int row = tid >> 2, jq = tid & 3;
        float e[16];
        float m = -1e30f;
        #pragma unroll
        for (int c = 0; c < 16; ++c) { e[c] = sh.QP[row][jq * 16 + c]; m = fmaxf(m, e[c]); }
        m = fmaxf(m, __shfl_xor(m, 1));
        m = fmaxf(m, __shfl_xor(m, 2));
        float s = 0.f;
        #pragma unroll
        for (int c = 0; c < 16; ++c) { e[c] = __expf(e[c] - m); s += e[c]; }
        s += __shfl_xor(s, 1);
        s += __shfl_xor(s, 2);
        float inv = 1.0f / s;
        #pragma unroll
        for (int c = 0; c < 16; ++c) sh.QP[row][jq * 16 + c] = e[c] * inv;
    }
    __syncthreads();

    float acco[4][4] = {};
    for (int c = 0; c < cNS; c += 4) {
        float4 p4[4], vt4[4];
        #pragma unroll
        for (int i = 0; i < 4; ++i) p4[i] = *(const float4*)&sh.QP[ty * 4 + i][c];
        #pragma unroll
        for (int j = 0; j < 4; ++j) vt4[j] = *(const float4*)&sh.Vt[tx + j * 16][c];
        #pragma unroll
        for (int i = 0; i < 4; ++i)
            #pragma unroll
            for (int j = 0; j < 4; ++j)
                acco[i][j] += p4[i].x * vt4[j].x + p4[i].y * vt4[j].y +
                              p4[i].z * vt4[j].z + p4[i].w * vt4[j].w;
    }
    size_t base = ((size_t)b * cNS) * cH + hh * cDH;
    #pragma unroll
    for (int i = 0; i < 4; ++i)
        #pragma unroll
        for (int j = 0; j < 4; ++j)
            ctx_bf[base + (size_t)(ty * 4 + i) * cH + tx + j * 16] =
                __float2bfloat16(acco[i][j]);
}

// ---------------------------------------------------------------------------
// 3a) O-GEMM + bias + GELU -> bf16 h, with ATOMIC-DRAIN fused LayerNorm.
//     Grid (24,8). Each block stores its 64x32 h tile, releases (threadfence)
//     and bumps cnt[gy]; the LAST arriver (atomicAdd ret == 23) acquires and
//     LayerNorms its 64 rows (wave-per-row). No spinning: non-last blocks
//     simply exit, so no deadlock under capture/replay.
// ---------------------------------------------------------------------------
__global__ __launch_bounds__(256) void ogemm_ln_kernel(
    const __hip_bfloat16* __restrict__ A,      // ctx_bf [M][H]
    const __hip_bfloat16* __restrict__ Wt,     // [H][H] n-major
    const float* __restrict__ bias,
    __hip_bfloat16* __restrict__ C,            // h bf16 [M][H]
    const float* __restrict__ g, const float* __restrict__ bb,
    __hip_bfloat16* __restrict__ xb,           // LN out bf16 [M][H]
    float* __restrict__ outf,                  // LN out f32 (last layer) or null
    int* __restrict__ cnt)                     // [8] drain counters (pre-zeroed)
{
    int tid  = threadIdx.x;
    int lane = tid & 63;
    int wave = tid >> 6;
    int l15 = lane & 15, q4 = lane >> 4;
    int gx = blockIdx.x, gy = blockIdx.y;
    int m0 = gy * 64 + wave * 16;
    int n0 = gx * 32;

    const __hip_bfloat16* Arow = A  + (size_t)(m0 + l15) * cH + q4 * 8;
    const __hip_bfloat16* Wr0  = Wt + (size_t)(n0 + l15) * cH + q4 * 8;
    const __hip_bfloat16* Wr1  = Wr0 + (size_t)16 * cH;

    f32x4 acc0 = {0.f, 0.f, 0.f, 0.f};
    f32x4 acc1 = {0.f, 0.f, 0.f, 0.f};
    #pragma unroll 8
    for (int k0 = 0; k0 < cH; k0 += 32) {
        bf16x8 a  = *(const bf16x8*)(Arow + k0);
        bf16x8 b0 = *(const bf16x8*)(Wr0 + k0);
        bf16x8 b1 = *(const bf16x8*)(Wr1 + k0);
        acc0 = __builtin_amdgcn_mfma_f32_16x16x32_bf16(a, b0, acc0, 0, 0, 0);
        acc1 = __builtin_amdgcn_mfma_f32_16x16x32_bf16(a, b1, acc1, 0, 0, 0);
    }
    #pragma unroll
    for (int nt = 0; nt < 2; ++nt) {
        const f32x4 acc = nt == 0 ? acc0 : acc1;
        int col = n0 + nt * 16 + l15;
        float bv = bias[col];
        #pragma unroll
        for (int r = 0; r < 4; ++r) {
            float v = acc[r] + bv;
            v = 0.5f * v * (1.0f + erff(v * 0.70710678118654752f));
            C[(size_t)(m0 + q4 * 4 + r) * cH + col] = __float2bfloat16(v);
        }
    }

    // ---------------- drain: last block of this row-group runs LN ----------
    __shared__ int isfin;
    __syncthreads();                       // all tile stores issued
    if (tid == 0) {
        __threadfence();                   // release: tile visible device-wide
        isfin = (atomicAdd(&cnt[gy], 1) == 23);
    }
    __syncthreads();
    if (!isfin) return;
    __threadfence();                       // acquire: see all 24 tiles

    // wave-per-row LN: 4 waves x 16 rows, 12 elems/lane (64*12 = 768)
    float gv[12], bv2[12];
    {
        const float* gp = g  + lane * 12;
        const float* bp = bb + lane * 12;
        #pragma unroll
        for (int j = 0; j < 3; ++j) {
            float4 g4 = *(const float4*)(gp + j * 4);
            float4 b4 = *(const float4*)(bp + j * 4);
            gv[j * 4 + 0] = g4.x; gv[j * 4 + 1] = g4.y;
            gv[j * 4 + 2] = g4.z; gv[j * 4 + 3] = g4.w;
            bv2[j * 4 + 0] = b4.x; bv2[j * 4 + 1] = b4.y;
            bv2[j * 4 + 2] = b4.z; bv2[j * 4 + 3] = b4.w;
        }
    }
    for (int r = wave; r < 64; r += 4) {
        int row = gy * 64 + r;
        const unsigned short* hr =
            (const unsigned short*)(C + (size_t)row * cH) + lane * 12;
        float v[12];
        #pragma unroll
        for (int j = 0; j < 3; ++j) {
            u16x4 q = *(const u16x4*)(hr + j * 4);
            v[j * 4 + 0] = b2f(q[0]); v[j * 4 + 1] = b2f(q[1]);
            v[j * 4 + 2] = b2f(q[2]); v[j * 4 + 3] = b2f(q[3]);
        }
        float s = 0.f;
        #pragma unroll
        for (int j = 0; j < 12; ++j) s += v[j];
        #pragma unroll
        for (int o = 32; o; o >>= 1) s += __shfl_xor(s, o);
        float mu = s * (1.0f / 768.0f);
        float ss = 0.f;
        #pragma unroll
        for (int j = 0; j < 12; ++j) { v[j] -= mu; ss += v[j] * v[j]; }
        #pragma unroll
        for (int o = 32; o; o >>= 1) ss += __shfl_xor(ss, o);
        float var = ss * (1.0f / 768.0f);
        float inv = rsqrtf(var + 1e-12f);
        float o12[12];
        #pragma unroll
        for (int j = 0; j < 12; ++j) o12[j] = v[j] * inv * gv[j] + bv2[j];

        unsigned short* xr = (unsigned short*)(xb + (size_t)row * cH) + lane * 12;
        #pragma unroll
        for (int j = 0; j < 3; ++j) {
            u16x4 q;
            q[0] = f2b(o12[j * 4 + 0]); q[1] = f2b(o12[j * 4 + 1]);
            q[2] = f2b(o12[j * 4 + 2]); q[3] = f2b(o12[j * 4 + 3]);
            *(u16x4*)(xr + j * 4) = q;
        }
        if (outf) {
            float* orow = outf + (size_t)row * cH + lane * 12;
            #pragma unroll
            for (int j = 0; j < 3; ++j) {
                float4 o4 = { o12[j * 4 + 0], o12[j * 4 + 1],
                              o12[j * 4 + 2], o12[j * 4 + 3] };
                *(float4*)(orow + j * 4) = o4;
            }
        }
    }
}

// ---------------------------------------------------------------------------
// 3b) Fallback: plain O-GEMM + bias + GELU (baseline-identical).
// ---------------------------------------------------------------------------
__global__ __launch_bounds__(256) void ogemm_kernel(
    const __hip_bfloat16* __restrict__ A,
    const __hip_bfloat16* __restrict__ Wt,
    const float* __restrict__ bias,
    __hip_bfloat16* __restrict__ C)
{
    int lane = threadIdx.x & 63;
    int wave = threadIdx.x >> 6;
    int l15 = lane & 15, q4 = lane >> 4;
    int m0 = blockIdx.y * 64 + wave * 16;
    int n0 = blockIdx.x * 32;

    const __hip_bfloat16* Arow = A  + (size_t)(m0 + l15) * cH + q4 * 8;
    const __hip_bfloat16* Wr0  = Wt + (size_t)(n0 + l15) * cH + q4 * 8;
    const __hip_bfloat16* Wr1  = Wr0 + (size_t)16 * cH;

    f32x4 acc0 = {0.f, 0.f, 0.f, 0.f};
    f32x4 acc1 = {0.f, 0.f, 0.f, 0.f};
    #pragma unroll 8
    for (int k0 = 0; k0 < cH; k0 += 32) {
        bf16x8 a  = *(const bf16x8*)(Arow + k0);
        bf16x8 b0 = *(const bf16x8*)(Wr0 + k0);
        bf16x8 b1 = *(const bf16x8*)(Wr1 + k0);
        acc0 = __builtin_amdgcn_mfma_f32_16x16x32_bf16(a, b0, acc0, 0, 0, 0);
        acc1 = __builtin_amdgcn_mfma_f32_16x16x32_bf16(a, b1, acc1, 0, 0, 0);
    }
    #pragma unroll
    for (int nt = 0; nt < 2; ++nt) {
        const f32x4 acc = nt == 0 ? acc0 : acc1;
        int col = n0 + nt * 16 + l15;
        float bv = bias[col];
        #pragma unroll
        for (int r = 0; r < 4; ++r) {
            float v = acc[r] + bv;
            v = 0.5f * v * (1.0f + erff(v * 0.70710678118654752f));
            C[(size_t)(m0 + q4 * 4 + r) * cH + col] = __float2bfloat16(v);
        }
    }
}

// ---------------------------------------------------------------------------
// 4) Fallback LayerNorm (baseline-identical). 512 blocks.
// ---------------------------------------------------------------------------
__global__ __launch_bounds__(256) void ln_kernel(
    const __hip_bfloat16* __restrict__ h, const float* __restrict__ g,
    const float* __restrict__ bb, __hip_bfloat16* __restrict__ xb,
    float* __restrict__ outf)
{
    int row = blockIdx.x;
    const __hip_bfloat16* r = h + (size_t)row * cH;
    int tid = threadIdx.x;
    float v0 = __bfloat162float(r[tid]);
    float v1 = __bfloat162float(r[tid + 256]);
    float v2 = __bfloat162float(r[tid + 512]);
    float s = v0 + v1 + v2;
    __shared__ float red[4];
    #pragma unroll
    for (int o = 32; o; o >>= 1) s += __shfl_xor(s, o);
    if ((tid & 63) == 0) red[tid >> 6] = s;
    __syncthreads();
    float mu = (red[0] + red[1] + red[2] + red[3]) * (1.0f / 768.0f);
    float d0 = v0 - mu, d1 = v1 - mu, d2 = v2 - mu;
    float ss = d0 * d0 + d1 * d1 + d2 * d2;
    __syncthreads();
    #pragma unroll
    for (int o = 32; o; o >>= 1) ss += __shfl_xor(ss, o);
    if ((tid & 63) == 0) red[tid >> 6] = ss;
    __syncthreads();
    float var = (red[0] + red[1] + red[2] + red[3]) * (1.0f / 768.0f);
    float inv = rsqrtf(var + 1e-12f);
    float o0 = d0 * inv * g[tid]       + bb[tid];
    float o1 = d1 * inv * g[tid + 256] + bb[tid + 256];
    float o2 = d2 * inv * g[tid + 512] + bb[tid + 512];
    __hip_bfloat16* xr = xb + (size_t)row * cH;
    xr[tid]       = __float2bfloat16(o0);
    xr[tid + 256] = __float2bfloat16(o1);
    xr[tid + 512] = __float2bfloat16(o2);
    if (outf) {
        float* orow = outf + (size_t)row * cH;
        orow[tid] = o0; orow[tid + 256] = o1; orow[tid + 512] = o2;
    }
}

// ---------------------------------------------------------------------------
extern "C" void kernel_launch(void* const* d_in, const int* in_sizes, int n_in,
                              void* d_out, int out_size, void* d_ws, size_t ws_size,
                              hipStream_t stream) {
    const int*   sent_ind = (const int*)d_in[0];
    const float* start    = (const float*)d_in[1];
    const float* Wq = (const float*)d_in[2];
    const float* bq = (const float*)d_in[3];
    const float* Wk = (const float*)d_in[4];
    const float* bk = (const float*)d_in[5];
    const float* Wv = (const float*)d_in[6];
    const float* bv = (const float*)d_in[7];
    const float* Wo = (const float*)d_in[8];
    const float* bo = (const float*)d_in[9];
    const float* ln_g = (const float*)d_in[10];
    const float* ln_b = (const float*)d_in[11];
    float* out = (float*)d_out;

    char* w = (char*)d_ws;
    __hip_bfloat16* wt     = (__hip_bfloat16*)w;                          // 8*H*H bf16
    __hip_bfloat16* x_bf   = (__hip_bfloat16*)(w + 9437184);              // M*H bf16
    __hip_bfloat16* ctx_bf = (__hip_bfloat16*)(w + 9437184 + 786432);     // M*H bf16
    __hip_bfloat16* hb     = (__hip_bfloat16*)(w + 9437184 + 2 * 786432); // M*H bf16
    const size_t base_sz   = 9437184 + 3 * (size_t)786432;                // 11,796,480

    // Fused-LN drain counters live past the baseline footprint; only use the
    // fused path if the workspace actually has room for them (OOB-safe).
    bool fused = ws_size >= base_sz + 256;
    int* lncnt = fused ? (int*)(w + base_sz) : nullptr;

    prep_kernel<<<cM + 576, 512, 0, stream>>>(sent_ind, start, x_bf,
                                              Wq, Wk, Wv, Wo, wt, lncnt);

    for (int i = 0; i < cL; ++i) {
        const __hip_bfloat16* wqkv = wt + (size_t)(i * 4) * cH * cH;     // q,k,v contiguous
        const __hip_bfloat16* wto  = wt + (size_t)(i * 4 + 3) * cH * cH;
        qkvattn_kernel<<<cB * cNH, 256, 0, stream>>>(
            x_bf, wqkv, bq + (size_t)i * cH, bk + (size_t)i * cH, bv + (size_t)i * cH,
            ctx_bf);
        if (fused) {
            ogemm_ln_kernel<<<dim3(24, 8), 256, 0, stream>>>(
                ctx_bf, wto, bo + (size_t)i * cH, hb,
                ln_g + (size_t)i * cH, ln_b + (size_t)i * cH,
                x_bf, (i == cL - 1) ? out : nullptr, lncnt + i * 8);
        } else {
            ogemm_kernel<<<dim3(24, 8), 256, 0, stream>>>(
                ctx_bf, wto, bo + (size_t)i * cH, hb);
            ln_kernel<<<cM, 256, 0, stream>>>(
                hb, ln_g + (size_t)i * cH, ln_b + (size_t)i * cH,
                x_bf, (i == cL - 1) ? out : nullptr);
        }
    }
}